// Round 1
// baseline (2137.563 us; speedup 1.0000x reference)
//
#include <hip/hip_runtime.h>
#include <cstdint>
#include <cstddef>

typedef _Float16 f16;
typedef _Float16 f16x8 __attribute__((ext_vector_type(8)));
typedef _Float16 f16x4 __attribute__((ext_vector_type(4)));
typedef _Float16 f16x2 __attribute__((ext_vector_type(2)));
typedef float f32x4 __attribute__((ext_vector_type(4)));

#define MFMA16(a, b, c) __builtin_amdgcn_mfma_f32_16x16x32_f16((a), (b), (c), 0, 0, 0)

// Problem sizes
// B=64, S=1024, D=128, H=256, 2H=512

// Workspace layout (bytes). Total ~194.8 MiB.
static constexpr size_t UT_OFF  = 0;                         // Ut  [2dir][2gate][256cc][256k] f16 = 524288
static constexpr size_t WT_OFF  = 524288;                    // Wt  [2dir][512cc2][128k] f16   = 262144
static constexpr size_t W1T_OFF = 786432;                    // W1t [512n][512k] f16           = 524288
static constexpr size_t XP_OFF  = 1310720;                   // xp  [2dir*4g][1024s][16b][512] f16 = 134217728
static constexpr size_t OUT_OFF = XP_OFF + 134217728;        // out16 [64b][1024s][512] f16    = 67108864
static constexpr size_t SC_OFF  = OUT_OFF + 67108864;        // scores [64][1024] f32          = 262144
static constexpr size_t AT_OFF  = SC_OFF + 262144;           // attn   [64][1024] f32          = 262144
static constexpr size_t PART_OFF= AT_OFF + 262144;           // partials [64][8][512] f32      = 1048576

// ---------------------------------------------------------------------------
// K0: transpose/convert params into MFMA-fragment-friendly fp16 layouts.
// Ut[u][cc][k]  = U_u[k][cc]   (u = dir*2+gate)
// Wt[d][cc2][k] = W_{d,gate}[k][cc2&255]  (gate = cc2>>8; order [z|h])
// W1t[n][k]     = W1[k][n]
// ---------------------------------------------------------------------------
__global__ void k0_prep(const float* __restrict__ Uzf, const float* __restrict__ Uhf,
                        const float* __restrict__ Uzb, const float* __restrict__ Uhb,
                        const float* __restrict__ Wzf, const float* __restrict__ Whf,
                        const float* __restrict__ Wzb, const float* __restrict__ Whb,
                        const float* __restrict__ W1,
                        f16* __restrict__ Ut, f16* __restrict__ Wt, f16* __restrict__ W1t)
{
    int tid = blockIdx.x * blockDim.x + threadIdx.x;
    int nthr = gridDim.x * blockDim.x;
    for (int i = tid; i < 4 * 256 * 256; i += nthr) {
        int u = i >> 16, cc = (i >> 8) & 255, k = i & 255;
        const float* U = (u == 0) ? Uzf : (u == 1) ? Uhf : (u == 2) ? Uzb : Uhb;
        Ut[i] = (f16)U[k * 256 + cc];
    }
    for (int i = tid; i < 2 * 512 * 128; i += nthr) {
        int dir = i >> 16, cc2 = (i >> 7) & 511, k = i & 127;
        const float* W = dir ? ((cc2 & 256) ? Whb : Wzb) : ((cc2 & 256) ? Whf : Wzf);
        Wt[i] = (f16)W[k * 256 + (cc2 & 255)];
    }
    for (int i = tid; i < 512 * 512; i += nthr) {
        int n = i >> 9, k = i & 511;
        W1t[i] = (f16)W1[k * 512 + n];
    }
}

// ---------------------------------------------------------------------------
// K1: input projections. One block = one (dir, batch-group g of 16, s).
// Computes (x_row @ [Wz|Wh]) + bias for 16 batches, 512 cols, writes one
// contiguous 16KB fp16 block of xp. Backward dir stored time-reversed so K2
// reads blocks in plain order. Transposed MFMA: D[cc2][b] = Wt[cc2][k]*x[b][k].
// ---------------------------------------------------------------------------
__launch_bounds__(256, 2)
__global__ void k1_xproj(const float* __restrict__ x, const f16* __restrict__ Wt,
                         const float* __restrict__ bzf, const float* __restrict__ bhf,
                         const float* __restrict__ bzb, const float* __restrict__ bhb,
                         f16* __restrict__ xp)
{
    int bid = blockIdx.x;
    int s = bid & 1023, g = (bid >> 10) & 3, dir = bid >> 12;
    int s_src = dir ? (1023 - s) : s;
    int tid = threadIdx.x, w = tid >> 6, lane = tid & 63, q = lane >> 4, l16 = lane & 15;
    __shared__ f16 tile[16][520];  // +8 f16 pad -> 2-way-free bank pattern

    // B fragments straight from global x (fp32 -> fp16): B[k][n=b]
    f16x8 bf[4];
    const float* xr = x + ((size_t)(g * 16 + l16) * 1024 + s_src) * 128;
#pragma unroll
    for (int kt = 0; kt < 4; ++kt) {
        int k0 = kt * 32 + q * 8;
        f32x4 a = *(const f32x4*)(xr + k0);
        f32x4 c = *(const f32x4*)(xr + k0 + 4);
        f16x8 v;
#pragma unroll
        for (int j = 0; j < 4; ++j) { v[j] = (f16)a[j]; v[4 + j] = (f16)c[j]; }
        bf[kt] = v;
    }
    // A fragments from Wt (wave w owns cc2 in [w*128, w*128+128))
    const f16* wt = Wt + (size_t)dir * 512 * 128;
    f16x8 af[8][4];
#pragma unroll
    for (int mt = 0; mt < 8; ++mt) {
        int cc2 = w * 128 + mt * 16 + l16;
#pragma unroll
        for (int kt = 0; kt < 4; ++kt)
            af[mt][kt] = *(const f16x8*)(wt + cc2 * 128 + kt * 32 + q * 8);
    }
    f32x4 acc[8];
#pragma unroll
    for (int mt = 0; mt < 8; ++mt) acc[mt] = (f32x4){0.f, 0.f, 0.f, 0.f};
#pragma unroll
    for (int kt = 0; kt < 4; ++kt)
#pragma unroll
        for (int mt = 0; mt < 8; ++mt)
            acc[mt] = MFMA16(af[mt][kt], bf[kt], acc[mt]);

    // epilogue: +bias, cvt fp16, stage to LDS (lane holds b=l16, 4 consecutive cc2)
#pragma unroll
    for (int mt = 0; mt < 8; ++mt) {
        int ccg = w * 128 + mt * 16 + q * 4;
        const float* bias = (ccg & 256) ? (dir ? bhb : bhf) : (dir ? bzb : bzf);
        f32x4 bi = *(const f32x4*)(bias + (ccg & 255));
        f16x4 o;
#pragma unroll
        for (int r = 0; r < 4; ++r) o[r] = (f16)(acc[mt][r] + bi[r]);
        *(f16x4*)&tile[l16][ccg] = o;
    }
    __syncthreads();
    // coalesced 16B store of the 16KB block
    f16* dst = xp + (size_t)((dir * 4 + g) * 1024 + s) * 8192;
#pragma unroll
    for (int i = 0; i < 4; ++i) {
        int chunk = i * 256 + tid;
        int bb = chunk >> 6, cc0 = (chunk & 63) * 8;
        *(f16x8*)(dst + bb * 512 + cc0) = *(const f16x8*)&tile[bb][cc0];
    }
}

// ---------------------------------------------------------------------------
// K2: the sequential recurrence. Grid = 8 blocks (2 dirs x 4 batch-groups),
// 512 threads (8 waves). U fragments resident in VGPRs (128/wave), h in LDS
// (fp32 master + fp16 MFMA copy), xz/xh double-buffered prefetch from xp.
// Transposed MFMA: D[cc][b] = Ut[cc][k] * h[b][k]; wave w owns cc [w*32,w*32+32)
// for BOTH gates so z and hc for the same element meet in-register.
// ---------------------------------------------------------------------------
__launch_bounds__(512, 2)
__global__ void k2_gru(const f16* __restrict__ Ut, const f16* __restrict__ xp,
                       f16* __restrict__ out16)
{
    int bid = blockIdx.x;
    int dir = bid >> 2, g = bid & 3;
    int tid = threadIdx.x, w = tid >> 6, lane = tid & 63, q = lane >> 4, l16 = lane & 15;
    __shared__ f16 h16[16][264];       // +16B pad: 2-way (free) LDS pattern
    __shared__ float h32[16][260];     // fp32 master state, +16B pad
    __shared__ f16 xs[2][16][520];     // double-buffered xz|xh staging, +16B pad

    for (int i = tid; i < 16 * 264; i += 512) (&h16[0][0])[i] = (f16)0.f;
    for (int i = tid; i < 16 * 260; i += 512) (&h32[0][0])[i] = 0.f;

    // resident U fragments: t = {z ccA, z ccB, hc ccA, hc ccB}
    f16x8 uf[4][8];
#pragma unroll
    for (int t = 0; t < 4; ++t) {
        int gate = t >> 1;
        int cc = w * 32 + (t & 1) * 16 + l16;
        const f16* up = Ut + ((size_t)(dir * 2 + gate) * 256 + cc) * 256;
#pragma unroll
        for (int kt = 0; kt < 8; ++kt)
            uf[t][kt] = *(const f16x8*)(up + kt * 32 + q * 8);
    }
    const f16* xpb = xp + (size_t)(dir * 4 + g) * 1024 * 8192;
    int bb = tid >> 5, cc0 = (tid & 31) * 16;
    {   // preload step 0
        f16x8 v0 = *(const f16x8*)(xpb + bb * 512 + cc0);
        f16x8 v1 = *(const f16x8*)(xpb + bb * 512 + cc0 + 8);
        *(f16x8*)&xs[0][bb][cc0] = v0;
        *(f16x8*)&xs[0][bb][cc0 + 8] = v1;
    }
    __syncthreads();

    size_t out_row_base = (size_t)(g * 16 + l16) * 1024;
    for (int s = 0; s < 1024; ++s) {
        int cur = s & 1, nxt = cur ^ 1;
        int sp = (s + 1 < 1024) ? (s + 1) : s;
        // prefetch next step's projections into registers (latency hidden by MFMA)
        f16x8 p0 = *(const f16x8*)(xpb + (size_t)sp * 8192 + bb * 512 + cc0);
        f16x8 p1 = *(const f16x8*)(xpb + (size_t)sp * 8192 + bb * 512 + cc0 + 8);
        // read h fragments + old h + xz/xh for this step (all into regs)
        f16x8 bf[8];
#pragma unroll
        for (int kt = 0; kt < 8; ++kt)
            bf[kt] = *(const f16x8*)&h16[l16][kt * 32 + q * 8];
        f32x4 hold[2]; f16x4 xzv[2], xhv[2];
#pragma unroll
        for (int p = 0; p < 2; ++p) {
            int ccg = w * 32 + p * 16 + q * 4;
            hold[p] = *(const f32x4*)&h32[l16][ccg];
            xzv[p] = *(const f16x4*)&xs[cur][l16][ccg];
            xhv[p] = *(const f16x4*)&xs[cur][l16][256 + ccg];
        }
        __syncthreads();   // all reads done before anyone writes h/xs

        f32x4 acc[4];
#pragma unroll
        for (int t = 0; t < 4; ++t) acc[t] = (f32x4){0.f, 0.f, 0.f, 0.f};
#pragma unroll
        for (int kt = 0; kt < 8; ++kt)
#pragma unroll
            for (int t = 0; t < 4; ++t)
                acc[t] = MFMA16(uf[t][kt], bf[kt], acc[t]);

        // stash prefetched projections for next step
        *(f16x8*)&xs[nxt][bb][cc0] = p0;
        *(f16x8*)&xs[nxt][bb][cc0 + 8] = p1;

        int s_out = dir ? (1023 - s) : s;
#pragma unroll
        for (int p = 0; p < 2; ++p) {
            int ccg = w * 32 + p * 16 + q * 4;
            f32x4 hn; f16x4 hh;
#pragma unroll
            for (int r = 0; r < 4; ++r) {
                float az = acc[p][r] + (float)xzv[p][r];
                float ah = acc[2 + p][r] + (float)xhv[p][r];
                float z = 1.f / (1.f + __expf(-az));
                float hc = 1.f - 2.f / (1.f + __expf(2.f * ah));
                float hv = z * hold[p][r] + (1.f - z) * hc;
                hn[r] = hv; hh[r] = (f16)hv;
            }
            *(f32x4*)&h32[l16][ccg] = hn;
            *(f16x4*)&h16[l16][ccg] = hh;
            *(f16x4*)(out16 + (out_row_base + s_out) * 512 + dir * 256 + ccg) = hh;
        }
        __syncthreads();   // h/xs writes visible before next step's reads
    }
}

// ---------------------------------------------------------------------------
// K3a: scores = tanh(out @ W1 + b1) @ w2 + b2. One block = (b, 64-row s chunk).
// Standard MFMA: D[row][n]; wave owns an n-range of 128; epilogue fuses
// tanh * w2 and reduces over n (in-reg + shfl over 16 lanes + LDS over waves).
// ---------------------------------------------------------------------------
__launch_bounds__(256, 2)
__global__ void k3_scores(const f16* __restrict__ out16, const f16* __restrict__ W1t,
                          const float* __restrict__ b1, const float* __restrict__ w2,
                          const float* __restrict__ b2, float* __restrict__ scores)
{
    int bid = blockIdx.x;
    int b = bid >> 4, sc = bid & 15, s0 = sc * 64;
    int tid = threadIdx.x, w = tid >> 6, lane = tid & 63, q = lane >> 4, l16 = lane & 15;
    f32x4 acc[4][8];
#pragma unroll
    for (int mt = 0; mt < 4; ++mt)
#pragma unroll
        for (int nt = 0; nt < 8; ++nt) acc[mt][nt] = (f32x4){0.f, 0.f, 0.f, 0.f};

    for (int kt = 0; kt < 16; ++kt) {
        f16x8 af[4];
#pragma unroll
        for (int mt = 0; mt < 4; ++mt) {
            size_t row = (size_t)b * 1024 + s0 + mt * 16 + l16;
            af[mt] = *(const f16x8*)(out16 + row * 512 + kt * 32 + q * 8);
        }
        f16x8 bfg[8];
#pragma unroll
        for (int nt = 0; nt < 8; ++nt) {
            int ncol = w * 128 + nt * 16 + l16;
            bfg[nt] = *(const f16x8*)(W1t + (size_t)ncol * 512 + kt * 32 + q * 8);
        }
#pragma unroll
        for (int mt = 0; mt < 4; ++mt)
#pragma unroll
            for (int nt = 0; nt < 8; ++nt)
                acc[mt][nt] = MFMA16(af[mt], bfg[nt], acc[mt][nt]);
    }
    float b1v[8], w2v[8];
#pragma unroll
    for (int nt = 0; nt < 8; ++nt) {
        int ncol = w * 128 + nt * 16 + l16;
        b1v[nt] = b1[ncol];
        w2v[nt] = w2[ncol];
    }
    __shared__ float spart[4][64];
    float rs[4][4];
#pragma unroll
    for (int mt = 0; mt < 4; ++mt)
#pragma unroll
        for (int r = 0; r < 4; ++r) {
            float ssum = 0.f;
#pragma unroll
            for (int nt = 0; nt < 8; ++nt) {
                float xv = acc[mt][nt][r] + b1v[nt];
                float t = 1.f - 2.f / (1.f + __expf(2.f * xv));
                ssum += t * w2v[nt];
            }
            rs[mt][r] = ssum;
        }
#pragma unroll
    for (int off = 1; off < 16; off <<= 1)
#pragma unroll
        for (int mt = 0; mt < 4; ++mt)
#pragma unroll
            for (int r = 0; r < 4; ++r)
                rs[mt][r] += __shfl_xor(rs[mt][r], off, 64);
    if (l16 == 0) {
#pragma unroll
        for (int mt = 0; mt < 4; ++mt)
#pragma unroll
            for (int r = 0; r < 4; ++r)
                spart[w][mt * 16 + q * 4 + r] = rs[mt][r];
    }
    __syncthreads();
    if (tid < 64) {
        float v = spart[0][tid] + spart[1][tid] + spart[2][tid] + spart[3][tid] + b2[0];
        scores[b * 1024 + s0 + tid] = v;
    }
}

// K3b1: softmax over time per batch.
__global__ void k3_softmax(const float* __restrict__ scores, float* __restrict__ attn)
{
    int b = blockIdx.x, tid = threadIdx.x;  // 256 threads, 4 scores each
    __shared__ float red[4];
    f32x4 v = *(const f32x4*)(scores + b * 1024 + tid * 4);
    float m = fmaxf(fmaxf(v[0], v[1]), fmaxf(v[2], v[3]));
#pragma unroll
    for (int off = 1; off < 64; off <<= 1) m = fmaxf(m, __shfl_xor(m, off, 64));
    if ((tid & 63) == 0) red[tid >> 6] = m;
    __syncthreads();
    m = fmaxf(fmaxf(red[0], red[1]), fmaxf(red[2], red[3]));
    __syncthreads();
    float e0 = __expf(v[0] - m), e1 = __expf(v[1] - m), e2 = __expf(v[2] - m), e3 = __expf(v[3] - m);
    float ssum = e0 + e1 + e2 + e3;
#pragma unroll
    for (int off = 1; off < 64; off <<= 1) ssum += __shfl_xor(ssum, off, 64);
    if ((tid & 63) == 0) red[tid >> 6] = ssum;
    __syncthreads();
    float inv = 1.f / (red[0] + red[1] + red[2] + red[3]);
    f32x4 o = {e0 * inv, e1 * inv, e2 * inv, e3 * inv};
    *(f32x4*)(attn + b * 1024 + tid * 4) = o;
}

// K3b2: partial weighted sums over s-chunks of 128.
__global__ void k3_wsum(const f16* __restrict__ out16, const float* __restrict__ attn,
                        float* __restrict__ part)
{
    int bid = blockIdx.x;
    int b = bid >> 3, ch = bid & 7;
    int tid = threadIdx.x;  // 256 threads, 2 cols each
    const f16* op = out16 + ((size_t)b * 1024 + ch * 128) * 512 + tid * 2;
    const float* ap = attn + b * 1024 + ch * 128;
    float a0 = 0.f, a1 = 0.f;
#pragma unroll 4
    for (int i = 0; i < 128; ++i) {
        float aw = ap[i];
        f16x2 xv = *(const f16x2*)(op + (size_t)i * 512);
        a0 += aw * (float)xv[0];
        a1 += aw * (float)xv[1];
    }
    part[(size_t)(b * 8 + ch) * 512 + tid * 2] = a0;
    part[(size_t)(b * 8 + ch) * 512 + tid * 2 + 1] = a1;
}

// K3b3: reduce 8 partials -> context (fp32 output).
__global__ void k3_final(const float* __restrict__ part, float* __restrict__ outp)
{
    int b = blockIdx.x, tid = threadIdx.x;
#pragma unroll
    for (int j = 0; j < 2; ++j) {
        int cc = tid * 2 + j;
        float ssum = 0.f;
#pragma unroll
        for (int ch = 0; ch < 8; ++ch) ssum += part[(size_t)(b * 8 + ch) * 512 + cc];
        outp[b * 512 + cc] = ssum;
    }
}

extern "C" void kernel_launch(void* const* d_in, const int* in_sizes, int n_in,
                              void* d_out, int out_size, void* d_ws, size_t ws_size,
                              hipStream_t stream)
{
    const float* x   = (const float*)d_in[0];
    const float* Wzf = (const float*)d_in[1];
    const float* Uzf = (const float*)d_in[2];
    const float* bzf = (const float*)d_in[3];
    const float* Whf = (const float*)d_in[4];
    const float* Uhf = (const float*)d_in[5];
    const float* bhf = (const float*)d_in[6];
    const float* Wzb = (const float*)d_in[7];
    const float* Uzb = (const float*)d_in[8];
    const float* bzb = (const float*)d_in[9];
    const float* Whb = (const float*)d_in[10];
    const float* Uhb = (const float*)d_in[11];
    const float* bhb = (const float*)d_in[12];
    const float* W1  = (const float*)d_in[13];
    const float* b1  = (const float*)d_in[14];
    const float* w2  = (const float*)d_in[15];
    const float* b2  = (const float*)d_in[16];
    float* outp = (float*)d_out;

    char* ws = (char*)d_ws;
    f16* Ut    = (f16*)(ws + UT_OFF);
    f16* Wt    = (f16*)(ws + WT_OFF);
    f16* W1t   = (f16*)(ws + W1T_OFF);
    f16* xp    = (f16*)(ws + XP_OFF);
    f16* o16   = (f16*)(ws + OUT_OFF);
    float* sc  = (float*)(ws + SC_OFF);
    float* at  = (float*)(ws + AT_OFF);
    float* pt  = (float*)(ws + PART_OFF);

    hipLaunchKernelGGL(k0_prep, dim3(256), dim3(256), 0, stream,
                       Uzf, Uhf, Uzb, Uhb, Wzf, Whf, Wzb, Whb, W1, Ut, Wt, W1t);
    hipLaunchKernelGGL(k1_xproj, dim3(8192), dim3(256), 0, stream,
                       x, Wt, bzf, bhf, bzb, bhb, xp);
    hipLaunchKernelGGL(k2_gru, dim3(8), dim3(512), 0, stream, Ut, xp, o16);
    hipLaunchKernelGGL(k3_scores, dim3(1024), dim3(256), 0, stream, o16, W1t, b1, w2, b2, sc);
    hipLaunchKernelGGL(k3_softmax, dim3(64), dim3(256), 0, stream, sc, at);
    hipLaunchKernelGGL(k3_wsum, dim3(512), dim3(256), 0, stream, o16, at, pt);
    hipLaunchKernelGGL(k3_final, dim3(64), dim3(256), 0, stream, pt, outp);
}

// Round 2
// 1524.425 us; speedup vs baseline: 1.4022x; 1.4022x over previous
//
#include <hip/hip_runtime.h>
#include <cstdint>
#include <cstddef>

typedef _Float16 f16;
typedef _Float16 f16x8 __attribute__((ext_vector_type(8)));
typedef _Float16 f16x4 __attribute__((ext_vector_type(4)));
typedef _Float16 f16x2 __attribute__((ext_vector_type(2)));
typedef float f32x4 __attribute__((ext_vector_type(4)));

#define MFMA16(a, b, c) __builtin_amdgcn_mfma_f32_16x16x32_f16((a), (b), (c), 0, 0, 0)

// Problem sizes: B=64, S=1024, D=128, H=256, 2H=512

// Workspace layout (bytes). Total ~194.8 MiB.
static constexpr size_t UT_OFF  = 0;                         // Ut  [2dir][2gate][256cc][256k] f16 = 524288
static constexpr size_t WT_OFF  = 524288;                    // Wt  [2dir][512cc2][128k] f16   = 262144
static constexpr size_t W1T_OFF = 786432;                    // W1t [512n][512k] f16           = 524288
static constexpr size_t XP_OFF  = 1310720;                   // xp2 [2dir*4g][1024s][8192] f16 = 134217728
static constexpr size_t OUT_OFF = XP_OFF + 134217728;        // out16 [64b][1024s][512] f16    = 67108864
static constexpr size_t SC_OFF  = OUT_OFF + 67108864;        // scores [64][1024] f32          = 262144
static constexpr size_t AT_OFF  = SC_OFF + 262144;           // attn   [64][1024] f32          = 262144
static constexpr size_t PART_OFF= AT_OFF + 262144;           // partials [64][8][512] f32      = 1048576

// ---------------------------------------------------------------------------
// K0: transpose/convert params into MFMA-fragment-friendly fp16 layouts.
// ---------------------------------------------------------------------------
__global__ void k0_prep(const float* __restrict__ Uzf, const float* __restrict__ Uhf,
                        const float* __restrict__ Uzb, const float* __restrict__ Uhb,
                        const float* __restrict__ Wzf, const float* __restrict__ Whf,
                        const float* __restrict__ Wzb, const float* __restrict__ Whb,
                        const float* __restrict__ W1,
                        f16* __restrict__ Ut, f16* __restrict__ Wt, f16* __restrict__ W1t)
{
    int tid = blockIdx.x * blockDim.x + threadIdx.x;
    int nthr = gridDim.x * blockDim.x;
    for (int i = tid; i < 4 * 256 * 256; i += nthr) {
        int u = i >> 16, cc = (i >> 8) & 255, k = i & 255;
        const float* U = (u == 0) ? Uzf : (u == 1) ? Uhf : (u == 2) ? Uzb : Uhb;
        Ut[i] = (f16)U[k * 256 + cc];
    }
    for (int i = tid; i < 2 * 512 * 128; i += nthr) {
        int dir = i >> 16, cc2 = (i >> 7) & 511, k = i & 127;
        const float* W = dir ? ((cc2 & 256) ? Whb : Wzb) : ((cc2 & 256) ? Whf : Wzf);
        Wt[i] = (f16)W[k * 256 + (cc2 & 255)];
    }
    for (int i = tid; i < 512 * 512; i += nthr) {
        int n = i >> 9, k = i & 511;
        W1t[i] = (f16)W1[k * 512 + n];
    }
}

// ---------------------------------------------------------------------------
// K1: input projections, LDS-free. One block = one (dir, g, s). Writes xp2 in
// K2's exact per-thread read layout:
//   flat = ((gate*2+p)*8 + w2)*256 + lane2*4 + r   with cc = w2*32+p*16+q*4+r,
//   lane2 = q*16 + l16 (b = l16). K2 reads are then 512B wave-coalesced.
// Backward dir stored time-reversed so K2 reads blocks in plain order.
// ---------------------------------------------------------------------------
__launch_bounds__(256, 2)
__global__ void k1_xproj(const float* __restrict__ x, const f16* __restrict__ Wt,
                         const float* __restrict__ bzf, const float* __restrict__ bhf,
                         const float* __restrict__ bzb, const float* __restrict__ bhb,
                         f16* __restrict__ xp2)
{
    int bid = blockIdx.x;
    int s = bid & 1023, g = (bid >> 10) & 3, dir = bid >> 12;
    int s_src = dir ? (1023 - s) : s;
    int tid = threadIdx.x, w = tid >> 6, lane = tid & 63, q = lane >> 4, l16 = lane & 15;

    // B fragments straight from global x (fp32 -> fp16): B[k][n=b]
    f16x8 bf[4];
    const float* xr = x + ((size_t)(g * 16 + l16) * 1024 + s_src) * 128;
#pragma unroll
    for (int kt = 0; kt < 4; ++kt) {
        int k0 = kt * 32 + q * 8;
        f32x4 a = *(const f32x4*)(xr + k0);
        f32x4 c = *(const f32x4*)(xr + k0 + 4);
        f16x8 v;
#pragma unroll
        for (int j = 0; j < 4; ++j) { v[j] = (f16)a[j]; v[4 + j] = (f16)c[j]; }
        bf[kt] = v;
    }
    // A fragments from Wt (wave w owns cc2 in [w*128, w*128+128))
    const f16* wt = Wt + (size_t)dir * 512 * 128;
    f16x8 af[8][4];
#pragma unroll
    for (int mt = 0; mt < 8; ++mt) {
        int cc2 = w * 128 + mt * 16 + l16;
#pragma unroll
        for (int kt = 0; kt < 4; ++kt)
            af[mt][kt] = *(const f16x8*)(wt + cc2 * 128 + kt * 32 + q * 8);
    }
    f32x4 acc[8];
#pragma unroll
    for (int mt = 0; mt < 8; ++mt) acc[mt] = (f32x4){0.f, 0.f, 0.f, 0.f};
#pragma unroll
    for (int kt = 0; kt < 4; ++kt)
#pragma unroll
        for (int mt = 0; mt < 8; ++mt)
            acc[mt] = MFMA16(af[mt][kt], bf[kt], acc[mt]);

    // epilogue: +bias, cvt fp16, direct scatter to xp2 (16-lane 128B segments)
    f16* dst = xp2 + (size_t)((dir * 4 + g) * 1024 + s) * 8192;
#pragma unroll
    for (int mt = 0; mt < 8; ++mt) {
        int ccg = w * 128 + mt * 16 + q * 4;
        int gate = ccg >> 8, c = ccg & 255;
        const float* bias = gate ? (dir ? bhb : bhf) : (dir ? bzb : bzf);
        f32x4 bi = *(const f32x4*)(bias + c);
        f16x4 o;
#pragma unroll
        for (int r = 0; r < 4; ++r) o[r] = (f16)(acc[mt][r] + bi[r]);
        int flat = ((gate * 2 + ((c >> 4) & 1)) * 8 + (c >> 5)) * 256 + (q * 16 + l16) * 4;
        *(f16x4*)(dst + flat) = o;
    }
}

// ---------------------------------------------------------------------------
// K2: sequential recurrence. Grid = 8 blocks (2 dirs x 4 batch-groups), 512
// threads. ONE barrier per step: h16 double-buffered in LDS; fp32 master h in
// registers; xz/xh prefetched one step ahead straight into registers (no LDS
// staging); out16 staged in a 9-deep LDS ring, flushed every 8 steps.
// Transposed MFMA: D[cc][b] = Ut[cc][k] * h[b][k].
// ---------------------------------------------------------------------------
__launch_bounds__(512, 2)
__global__ void k2_gru(const f16* __restrict__ Ut, const f16* __restrict__ xp2,
                       f16* __restrict__ out16)
{
    int bid = blockIdx.x;
    int dir = bid >> 2, g = bid & 3;
    int tid = threadIdx.x, w = tid >> 6, lane = tid & 63, q = lane >> 4, l16 = lane & 15;
    __shared__ f16 h16[2][16][264];   // double-buffered fp16 h (row stride 528B, 16B-mult)
    __shared__ f16 ob[9][16][264];    // out staging ring, 9 slots x 8KB

    for (int i = tid; i < 2 * 16 * 264; i += 512) (&h16[0][0][0])[i] = (f16)0.f;

    // resident U fragments: t = {z p0, z p1, hc p0, hc p1}; cc = w*32+(t&1)*16+l16
    f16x8 uf[4][8];
#pragma unroll
    for (int t = 0; t < 4; ++t) {
        int gate = t >> 1;
        int cc = w * 32 + (t & 1) * 16 + l16;
        const f16* up = Ut + ((size_t)(dir * 2 + gate) * 256 + cc) * 256;
#pragma unroll
        for (int kt = 0; kt < 8; ++kt)
            uf[t][kt] = *(const f16x8*)(up + kt * 32 + q * 8);
    }

    const f16* xb = xp2 + (size_t)(dir * 4 + g) * 1024 * 8192;
    int offs[4];
#pragma unroll
    for (int t = 0; t < 4; ++t) {
        int gate = t >> 1, p = t & 1;
        offs[t] = ((gate * 2 + p) * 8 + w) * 256 + lane * 4;
    }
    f16x4 cx[4];
#pragma unroll
    for (int t = 0; t < 4; ++t) cx[t] = *(const f16x4*)(xb + offs[t]);
    f32x4 hold[2];
    hold[0] = (f32x4){0.f, 0.f, 0.f, 0.f};
    hold[1] = (f32x4){0.f, 0.f, 0.f, 0.f};

    __syncthreads();

    int slot = 0, base_slot = 0;
    for (int s = 0; s < 1024; ++s) {
        int cur = s & 1, nxt = cur ^ 1;
        // prefetch next step's gate inputs into registers (512B coalesced/wave)
        const f16* px = xb + (size_t)((s + 1 < 1024) ? s + 1 : s) * 8192;
        f16x4 nx[4];
#pragma unroll
        for (int t = 0; t < 4; ++t) nx[t] = *(const f16x4*)(px + offs[t]);

        // h fragments for this step
        f16x8 bf[8];
#pragma unroll
        for (int kt = 0; kt < 8; ++kt)
            bf[kt] = *(const f16x8*)&h16[cur][l16][kt * 32 + q * 8];

        // acc init = xz/xh (saves the epilogue adds)
        f32x4 acc[4];
#pragma unroll
        for (int t = 0; t < 4; ++t)
#pragma unroll
            for (int r = 0; r < 4; ++r) acc[t][r] = (float)cx[t][r];

#pragma unroll
        for (int kt = 0; kt < 8; ++kt)
#pragma unroll
            for (int t = 0; t < 4; ++t)
                acc[t] = MFMA16(uf[t][kt], bf[kt], acc[t]);

        // flush out ring every 8 steps (reads slots written before last barrier;
        // this step writes slot s%9 which is not in the flushed set)
        if ((s & 7) == 0 && s) {
            int base = s - 8;
#pragma unroll
            for (int i = 0; i < 8; ++i) {
                int chunk = i * 512 + tid;
                int st = chunk >> 9, rem = chunk & 511;
                int bb2 = rem >> 5, c16 = (rem & 31) * 8;
                int sl = base_slot + st; if (sl >= 9) sl -= 9;
                int sidx = base + st;
                int s_out = dir ? (1023 - sidx) : sidx;
                f16x8 v = *(const f16x8*)&ob[sl][bb2][c16];
                *(f16x8*)(out16 + ((size_t)(g * 16 + bb2) * 1024 + s_out) * 512 + dir * 256 + c16) = v;
            }
            base_slot += 8; if (base_slot >= 9) base_slot -= 9;
        }

        // elementwise gate math: h' = [h(1+E2)+E1(1-E2)] / [(1+E1)(1+E2)],
        // E1 = exp(-az) (sigmoid), E2 = exp(-2ah) (tanh). 2 exp + 1 rcp / elem.
#pragma unroll
        for (int p = 0; p < 2; ++p) {
            f32x4 hn; f16x4 hh;
#pragma unroll
            for (int r = 0; r < 4; ++r) {
                float az = acc[p][r];
                float ah = acc[2 + p][r];
                float E1 = __expf(-az);
                float E2 = __expf(-2.f * ah);
                float h0 = hold[p][r];
                float num = __builtin_fmaf(h0, E2, h0) + __builtin_fmaf(-E1, E2, E1);
                float den = (1.f + E1) * (1.f + E2);
                float hv = num * __builtin_amdgcn_rcpf(den);
                hn[r] = hv; hh[r] = (f16)hv;
            }
            hold[p] = hn;
            int ccg = w * 32 + p * 16 + q * 4;
            *(f16x4*)&h16[nxt][l16][ccg] = hh;
            *(f16x4*)&ob[slot][l16][ccg] = hh;
        }

#pragma unroll
        for (int t = 0; t < 4; ++t) cx[t] = nx[t];
        slot += 1; if (slot >= 9) slot = 0;
        __syncthreads();
    }
    // final flush: steps 1016..1023
    {
        int base = 1016;
#pragma unroll
        for (int i = 0; i < 8; ++i) {
            int chunk = i * 512 + tid;
            int st = chunk >> 9, rem = chunk & 511;
            int bb2 = rem >> 5, c16 = (rem & 31) * 8;
            int sl = base_slot + st; if (sl >= 9) sl -= 9;
            int sidx = base + st;
            int s_out = dir ? (1023 - sidx) : sidx;
            f16x8 v = *(const f16x8*)&ob[sl][bb2][c16];
            *(f16x8*)(out16 + ((size_t)(g * 16 + bb2) * 1024 + s_out) * 512 + dir * 256 + c16) = v;
        }
    }
}

// ---------------------------------------------------------------------------
// K3a: scores = tanh(out @ W1 + b1) @ w2 + b2.
// ---------------------------------------------------------------------------
__launch_bounds__(256, 2)
__global__ void k3_scores(const f16* __restrict__ out16, const f16* __restrict__ W1t,
                          const float* __restrict__ b1, const float* __restrict__ w2,
                          const float* __restrict__ b2, float* __restrict__ scores)
{
    int bid = blockIdx.x;
    int b = bid >> 4, sc = bid & 15, s0 = sc * 64;
    int tid = threadIdx.x, w = tid >> 6, lane = tid & 63, q = lane >> 4, l16 = lane & 15;
    f32x4 acc[4][8];
#pragma unroll
    for (int mt = 0; mt < 4; ++mt)
#pragma unroll
        for (int nt = 0; nt < 8; ++nt) acc[mt][nt] = (f32x4){0.f, 0.f, 0.f, 0.f};

    for (int kt = 0; kt < 16; ++kt) {
        f16x8 af[4];
#pragma unroll
        for (int mt = 0; mt < 4; ++mt) {
            size_t row = (size_t)b * 1024 + s0 + mt * 16 + l16;
            af[mt] = *(const f16x8*)(out16 + row * 512 + kt * 32 + q * 8);
        }
        f16x8 bfg[8];
#pragma unroll
        for (int nt = 0; nt < 8; ++nt) {
            int ncol = w * 128 + nt * 16 + l16;
            bfg[nt] = *(const f16x8*)(W1t + (size_t)ncol * 512 + kt * 32 + q * 8);
        }
#pragma unroll
        for (int mt = 0; mt < 4; ++mt)
#pragma unroll
            for (int nt = 0; nt < 8; ++nt)
                acc[mt][nt] = MFMA16(af[mt], bfg[nt], acc[mt][nt]);
    }
    float b1v[8], w2v[8];
#pragma unroll
    for (int nt = 0; nt < 8; ++nt) {
        int ncol = w * 128 + nt * 16 + l16;
        b1v[nt] = b1[ncol];
        w2v[nt] = w2[ncol];
    }
    __shared__ float spart[4][64];
    float rs[4][4];
#pragma unroll
    for (int mt = 0; mt < 4; ++mt)
#pragma unroll
        for (int r = 0; r < 4; ++r) {
            float ssum = 0.f;
#pragma unroll
            for (int nt = 0; nt < 8; ++nt) {
                float xv = acc[mt][nt][r] + b1v[nt];
                float t = 1.f - 2.f / (1.f + __expf(2.f * xv));
                ssum += t * w2v[nt];
            }
            rs[mt][r] = ssum;
        }
#pragma unroll
    for (int off = 1; off < 16; off <<= 1)
#pragma unroll
        for (int mt = 0; mt < 4; ++mt)
#pragma unroll
            for (int r = 0; r < 4; ++r)
                rs[mt][r] += __shfl_xor(rs[mt][r], off, 64);
    if (l16 == 0) {
#pragma unroll
        for (int mt = 0; mt < 4; ++mt)
#pragma unroll
            for (int r = 0; r < 4; ++r)
                spart[w][mt * 16 + q * 4 + r] = rs[mt][r];
    }
    __syncthreads();
    if (tid < 64) {
        float v = spart[0][tid] + spart[1][tid] + spart[2][tid] + spart[3][tid] + b2[0];
        scores[b * 1024 + s0 + tid] = v;
    }
}

// K3b1: softmax over time per batch.
__global__ void k3_softmax(const float* __restrict__ scores, float* __restrict__ attn)
{
    int b = blockIdx.x, tid = threadIdx.x;
    __shared__ float red[4];
    f32x4 v = *(const f32x4*)(scores + b * 1024 + tid * 4);
    float m = fmaxf(fmaxf(v[0], v[1]), fmaxf(v[2], v[3]));
#pragma unroll
    for (int off = 1; off < 64; off <<= 1) m = fmaxf(m, __shfl_xor(m, off, 64));
    if ((tid & 63) == 0) red[tid >> 6] = m;
    __syncthreads();
    m = fmaxf(fmaxf(red[0], red[1]), fmaxf(red[2], red[3]));
    __syncthreads();
    float e0 = __expf(v[0] - m), e1 = __expf(v[1] - m), e2 = __expf(v[2] - m), e3 = __expf(v[3] - m);
    float ssum = e0 + e1 + e2 + e3;
#pragma unroll
    for (int off = 1; off < 64; off <<= 1) ssum += __shfl_xor(ssum, off, 64);
    if ((tid & 63) == 0) red[tid >> 6] = ssum;
    __syncthreads();
    float inv = 1.f / (red[0] + red[1] + red[2] + red[3]);
    f32x4 o = {e0 * inv, e1 * inv, e2 * inv, e3 * inv};
    *(f32x4*)(attn + b * 1024 + tid * 4) = o;
}

// K3b2: partial weighted sums over s-chunks of 128.
__global__ void k3_wsum(const f16* __restrict__ out16, const float* __restrict__ attn,
                        float* __restrict__ part)
{
    int bid = blockIdx.x;
    int b = bid >> 3, ch = bid & 7;
    int tid = threadIdx.x;
    const f16* op = out16 + ((size_t)b * 1024 + ch * 128) * 512 + tid * 2;
    const float* ap = attn + b * 1024 + ch * 128;
    float a0 = 0.f, a1 = 0.f;
#pragma unroll 4
    for (int i = 0; i < 128; ++i) {
        float aw = ap[i];
        f16x2 xv = *(const f16x2*)(op + (size_t)i * 512);
        a0 += aw * (float)xv[0];
        a1 += aw * (float)xv[1];
    }
    part[(size_t)(b * 8 + ch) * 512 + tid * 2] = a0;
    part[(size_t)(b * 8 + ch) * 512 + tid * 2 + 1] = a1;
}

// K3b3: reduce 8 partials -> context (fp32 output).
__global__ void k3_final(const float* __restrict__ part, float* __restrict__ outp)
{
    int b = blockIdx.x, tid = threadIdx.x;
#pragma unroll
    for (int j = 0; j < 2; ++j) {
        int cc = tid * 2 + j;
        float ssum = 0.f;
#pragma unroll
        for (int ch = 0; ch < 8; ++ch) ssum += part[(size_t)(b * 8 + ch) * 512 + cc];
        outp[b * 512 + cc] = ssum;
    }
}

extern "C" void kernel_launch(void* const* d_in, const int* in_sizes, int n_in,
                              void* d_out, int out_size, void* d_ws, size_t ws_size,
                              hipStream_t stream)
{
    const float* x   = (const float*)d_in[0];
    const float* Wzf = (const float*)d_in[1];
    const float* Uzf = (const float*)d_in[2];
    const float* bzf = (const float*)d_in[3];
    const float* Whf = (const float*)d_in[4];
    const float* Uhf = (const float*)d_in[5];
    const float* bhf = (const float*)d_in[6];
    const float* Wzb = (const float*)d_in[7];
    const float* Uzb = (const float*)d_in[8];
    const float* bzb = (const float*)d_in[9];
    const float* Whb = (const float*)d_in[10];
    const float* Uhb = (const float*)d_in[11];
    const float* bhb = (const float*)d_in[12];
    const float* W1  = (const float*)d_in[13];
    const float* b1  = (const float*)d_in[14];
    const float* w2  = (const float*)d_in[15];
    const float* b2  = (const float*)d_in[16];
    float* outp = (float*)d_out;

    char* ws = (char*)d_ws;
    f16* Ut    = (f16*)(ws + UT_OFF);
    f16* Wt    = (f16*)(ws + WT_OFF);
    f16* W1t   = (f16*)(ws + W1T_OFF);
    f16* xp2   = (f16*)(ws + XP_OFF);
    f16* o16   = (f16*)(ws + OUT_OFF);
    float* sc  = (float*)(ws + SC_OFF);
    float* at  = (float*)(ws + AT_OFF);
    float* pt  = (float*)(ws + PART_OFF);

    hipLaunchKernelGGL(k0_prep, dim3(256), dim3(256), 0, stream,
                       Uzf, Uhf, Uzb, Uhb, Wzf, Whf, Wzb, Whb, W1, Ut, Wt, W1t);
    hipLaunchKernelGGL(k1_xproj, dim3(8192), dim3(256), 0, stream,
                       x, Wt, bzf, bhf, bzb, bhb, xp2);
    hipLaunchKernelGGL(k2_gru, dim3(8), dim3(512), 0, stream, Ut, xp2, o16);
    hipLaunchKernelGGL(k3_scores, dim3(1024), dim3(256), 0, stream, o16, W1t, b1, w2, b2, sc);
    hipLaunchKernelGGL(k3_softmax, dim3(64), dim3(256), 0, stream, sc, at);
    hipLaunchKernelGGL(k3_wsum, dim3(512), dim3(256), 0, stream, o16, at, pt);
    hipLaunchKernelGGL(k3_final, dim3(64), dim3(256), 0, stream, pt, outp);
}

// Round 3
// 1434.658 us; speedup vs baseline: 1.4899x; 1.0626x over previous
//
#include <hip/hip_runtime.h>
#include <cstdint>
#include <cstddef>

typedef _Float16 f16;
typedef _Float16 f16x8 __attribute__((ext_vector_type(8)));
typedef _Float16 f16x4 __attribute__((ext_vector_type(4)));
typedef _Float16 f16x2 __attribute__((ext_vector_type(2)));
typedef float f32x4 __attribute__((ext_vector_type(4)));

#define MFMA16(a, b, c) __builtin_amdgcn_mfma_f32_16x16x32_f16((a), (b), (c), 0, 0, 0)

// Problem sizes: B=64, S=1024, D=128, H=256, 2H=512

// Workspace layout (bytes). Total ~194.8 MiB.
static constexpr size_t UT_OFF  = 0;                         // Ut  [2dir][2gate][256cc][256k] f16 = 524288
static constexpr size_t WT_OFF  = 524288;                    // Wt  [2dir][512cc2][128k] f16   = 262144
static constexpr size_t W1T_OFF = 786432;                    // W1t [512n][512k] f16           = 524288
static constexpr size_t XP_OFF  = 1310720;                   // xp2 [2dir*4g][1024s][8192] f16 = 134217728
static constexpr size_t OUT_OFF = XP_OFF + 134217728;        // out16 [64b][1024s][512] f16    = 67108864
static constexpr size_t SC_OFF  = OUT_OFF + 67108864;        // scores [64][1024] f32          = 262144
static constexpr size_t AT_OFF  = SC_OFF + 262144;           // attn   [64][1024] f32          = 262144
static constexpr size_t PART_OFF= AT_OFF + 262144;           // partials [64][8][512] f32      = 1048576

// ---------------------------------------------------------------------------
// K0: transpose/convert params into MFMA-fragment-friendly fp16 layouts.
// ---------------------------------------------------------------------------
__global__ void k0_prep(const float* __restrict__ Uzf, const float* __restrict__ Uhf,
                        const float* __restrict__ Uzb, const float* __restrict__ Uhb,
                        const float* __restrict__ Wzf, const float* __restrict__ Whf,
                        const float* __restrict__ Wzb, const float* __restrict__ Whb,
                        const float* __restrict__ W1,
                        f16* __restrict__ Ut, f16* __restrict__ Wt, f16* __restrict__ W1t)
{
    int tid = blockIdx.x * blockDim.x + threadIdx.x;
    int nthr = gridDim.x * blockDim.x;
    for (int i = tid; i < 4 * 256 * 256; i += nthr) {
        int u = i >> 16, cc = (i >> 8) & 255, k = i & 255;
        const float* U = (u == 0) ? Uzf : (u == 1) ? Uhf : (u == 2) ? Uzb : Uhb;
        Ut[i] = (f16)U[k * 256 + cc];
    }
    for (int i = tid; i < 2 * 512 * 128; i += nthr) {
        int dir = i >> 16, cc2 = (i >> 7) & 511, k = i & 127;
        const float* W = dir ? ((cc2 & 256) ? Whb : Wzb) : ((cc2 & 256) ? Whf : Wzf);
        Wt[i] = (f16)W[k * 256 + (cc2 & 255)];
    }
    for (int i = tid; i < 512 * 512; i += nthr) {
        int n = i >> 9, k = i & 511;
        W1t[i] = (f16)W1[k * 512 + n];
    }
}

// ---------------------------------------------------------------------------
// K1: input projections, LDS-free. One block = one (dir, g, s). Writes xp2 in
// K2's exact per-thread read layout:
//   flat = ((gate*2+p)*8 + w2)*256 + lane2*4 + r   with cc = w2*32+p*16+q*4+r,
//   lane2 = q*16 + l16 (b = l16). K2 reads are then 512B wave-coalesced.
// Backward dir stored time-reversed so K2 reads blocks in plain order.
// ---------------------------------------------------------------------------
__launch_bounds__(256, 2)
__global__ void k1_xproj(const float* __restrict__ x, const f16* __restrict__ Wt,
                         const float* __restrict__ bzf, const float* __restrict__ bhf,
                         const float* __restrict__ bzb, const float* __restrict__ bhb,
                         f16* __restrict__ xp2)
{
    int bid = blockIdx.x;
    int s = bid & 1023, g = (bid >> 10) & 3, dir = bid >> 12;
    int s_src = dir ? (1023 - s) : s;
    int tid = threadIdx.x, w = tid >> 6, lane = tid & 63, q = lane >> 4, l16 = lane & 15;

    // B fragments straight from global x (fp32 -> fp16): B[k][n=b]
    f16x8 bf[4];
    const float* xr = x + ((size_t)(g * 16 + l16) * 1024 + s_src) * 128;
#pragma unroll
    for (int kt = 0; kt < 4; ++kt) {
        int k0 = kt * 32 + q * 8;
        f32x4 a = *(const f32x4*)(xr + k0);
        f32x4 c = *(const f32x4*)(xr + k0 + 4);
        f16x8 v;
#pragma unroll
        for (int j = 0; j < 4; ++j) { v[j] = (f16)a[j]; v[4 + j] = (f16)c[j]; }
        bf[kt] = v;
    }
    // A fragments from Wt (wave w owns cc2 in [w*128, w*128+128))
    const f16* wt = Wt + (size_t)dir * 512 * 128;
    f16x8 af[8][4];
#pragma unroll
    for (int mt = 0; mt < 8; ++mt) {
        int cc2 = w * 128 + mt * 16 + l16;
#pragma unroll
        for (int kt = 0; kt < 4; ++kt)
            af[mt][kt] = *(const f16x8*)(wt + cc2 * 128 + kt * 32 + q * 8);
    }
    f32x4 acc[8];
#pragma unroll
    for (int mt = 0; mt < 8; ++mt) acc[mt] = (f32x4){0.f, 0.f, 0.f, 0.f};
#pragma unroll
    for (int kt = 0; kt < 4; ++kt)
#pragma unroll
        for (int mt = 0; mt < 8; ++mt)
            acc[mt] = MFMA16(af[mt][kt], bf[kt], acc[mt]);

    // epilogue: +bias, cvt fp16, direct scatter to xp2 (16-lane 128B segments)
    f16* dst = xp2 + (size_t)((dir * 4 + g) * 1024 + s) * 8192;
#pragma unroll
    for (int mt = 0; mt < 8; ++mt) {
        int ccg = w * 128 + mt * 16 + q * 4;
        int gate = ccg >> 8, c = ccg & 255;
        const float* bias = gate ? (dir ? bhb : bhf) : (dir ? bzb : bzf);
        f32x4 bi = *(const f32x4*)(bias + c);
        f16x4 o;
#pragma unroll
        for (int r = 0; r < 4; ++r) o[r] = (f16)(acc[mt][r] + bi[r]);
        int flat = ((gate * 2 + ((c >> 4) & 1)) * 8 + (c >> 5)) * 256 + (q * 16 + l16) * 4;
        *(f16x4*)(dst + flat) = o;
    }
}

// ---------------------------------------------------------------------------
// K2: sequential recurrence. Grid = 8 blocks (2 dirs x 4 batch-groups), 512
// threads. U fragments loaded ONCE via volatile loads (cannot be
// rematerialized -> must stay resident in VGPRs; ~230 VGPR total, under the
// 256 cap of launch_bounds(512,2)). Two-level loop: 8 fully-unrolled steps
// (one barrier each), then a staged 64KB flush of out16.
// Transposed MFMA: D[cc][b] = Ut[cc][k] * h[b][k].
// ---------------------------------------------------------------------------
__launch_bounds__(512, 2)
__global__ void k2_gru(const f16* __restrict__ Ut, const f16* __restrict__ xp2,
                       f16* __restrict__ out16)
{
    int bid = blockIdx.x;
    int dir = bid >> 2, g = bid & 3;
    int tid = threadIdx.x, w = tid >> 6, lane = tid & 63, q = lane >> 4, l16 = lane & 15;
    __shared__ f16 h16[2][16][264];   // double-buffered fp16 h
    __shared__ f16 ob[8][16][264];    // out staging, 8 slots x 8.25KB

    for (int i = tid; i < 2 * 16 * 264; i += 512) (&h16[0][0][0])[i] = (f16)0.f;

    // resident U fragments: t = {z p0, z p1, hc p0, hc p1}; cc = w*32+(t&1)*16+l16
    // volatile: forbids rematerialization inside the loop -> stays in VGPRs.
    f16x8 uf[4][8];
#pragma unroll
    for (int t = 0; t < 4; ++t) {
        int gate = t >> 1;
        int cc = w * 32 + (t & 1) * 16 + l16;
        const f16* up = Ut + ((size_t)(dir * 2 + gate) * 256 + cc) * 256;
#pragma unroll
        for (int kt = 0; kt < 8; ++kt)
            uf[t][kt] = *(const volatile f16x8*)(up + kt * 32 + q * 8);
    }

    const f16* xb = xp2 + (size_t)(dir * 4 + g) * 1024 * 8192;
    int offs[4];
#pragma unroll
    for (int t = 0; t < 4; ++t) {
        int gate = t >> 1, p = t & 1;
        offs[t] = ((gate * 2 + p) * 8 + w) * 256 + lane * 4;
    }
    f16x4 cx[4];
#pragma unroll
    for (int t = 0; t < 4; ++t) cx[t] = *(const f16x4*)(xb + offs[t]);
    f32x4 hold[2];
    hold[0] = (f32x4){0.f, 0.f, 0.f, 0.f};
    hold[1] = (f32x4){0.f, 0.f, 0.f, 0.f};

    __syncthreads();

    for (int so = 0; so < 1024; so += 8) {
#pragma unroll
        for (int si = 0; si < 8; ++si) {
            int s = so + si;
            int cur = s & 1, nxt = cur ^ 1;
            // prefetch next step's gate inputs (512B coalesced per wave)
            const f16* px = xb + (size_t)((s + 1 < 1024) ? s + 1 : s) * 8192;
            f16x4 nx[4];
#pragma unroll
            for (int t = 0; t < 4; ++t) nx[t] = *(const f16x4*)(px + offs[t]);

            // h fragments for this step
            f16x8 bf[8];
#pragma unroll
            for (int kt = 0; kt < 8; ++kt)
                bf[kt] = *(const f16x8*)&h16[cur][l16][kt * 32 + q * 8];

            // acc init = xz/xh
            f32x4 acc[4];
#pragma unroll
            for (int t = 0; t < 4; ++t)
#pragma unroll
                for (int r = 0; r < 4; ++r) acc[t][r] = (float)cx[t][r];

#pragma unroll
            for (int kt = 0; kt < 8; ++kt)
#pragma unroll
                for (int t = 0; t < 4; ++t)
                    acc[t] = MFMA16(uf[t][kt], bf[kt], acc[t]);

            // gate math: h' = [h(1+E2)+E1(1-E2)] / [(1+E1)(1+E2)],
            // E1 = exp(-az), E2 = exp(-2ah). 2 exp + 1 rcp per element.
#pragma unroll
            for (int p = 0; p < 2; ++p) {
                f32x4 hn; f16x4 hh;
#pragma unroll
                for (int r = 0; r < 4; ++r) {
                    float az = acc[p][r];
                    float ah = acc[2 + p][r];
                    float E1 = __expf(-az);
                    float E2 = __expf(-2.f * ah);
                    float h0 = hold[p][r];
                    float num = __builtin_fmaf(h0, E2, h0) + __builtin_fmaf(-E1, E2, E1);
                    float den = (1.f + E1) * (1.f + E2);
                    float hv = num * __builtin_amdgcn_rcpf(den);
                    hn[r] = hv; hh[r] = (f16)hv;
                }
                hold[p] = hn;
                int ccg = w * 32 + p * 16 + q * 4;
                *(f16x4*)&h16[nxt][l16][ccg] = hh;
                *(f16x4*)&ob[si][l16][ccg] = hh;
            }

#pragma unroll
            for (int t = 0; t < 4; ++t) cx[t] = nx[t];
            __syncthreads();
        }
        // flush steps so..so+7 (64KB) with coalesced 16B stores
#pragma unroll
        for (int i = 0; i < 8; ++i) {
            int chunk = i * 512 + tid;
            int st = chunk >> 9, rem = chunk & 511;
            int bb2 = rem >> 5, c16 = (rem & 31) * 8;
            int sidx = so + st;
            int s_out = dir ? (1023 - sidx) : sidx;
            f16x8 v = *(const f16x8*)&ob[st][bb2][c16];
            *(f16x8*)(out16 + ((size_t)(g * 16 + bb2) * 1024 + s_out) * 512 + dir * 256 + c16) = v;
        }
        __syncthreads();  // ob reads done before next inner loop overwrites
    }
}

// ---------------------------------------------------------------------------
// K3a: scores = tanh(out @ W1 + b1) @ w2 + b2.
// ---------------------------------------------------------------------------
__launch_bounds__(256, 2)
__global__ void k3_scores(const f16* __restrict__ out16, const f16* __restrict__ W1t,
                          const float* __restrict__ b1, const float* __restrict__ w2,
                          const float* __restrict__ b2, float* __restrict__ scores)
{
    int bid = blockIdx.x;
    int b = bid >> 4, sc = bid & 15, s0 = sc * 64;
    int tid = threadIdx.x, w = tid >> 6, lane = tid & 63, q = lane >> 4, l16 = lane & 15;
    f32x4 acc[4][8];
#pragma unroll
    for (int mt = 0; mt < 4; ++mt)
#pragma unroll
        for (int nt = 0; nt < 8; ++nt) acc[mt][nt] = (f32x4){0.f, 0.f, 0.f, 0.f};

    for (int kt = 0; kt < 16; ++kt) {
        f16x8 af[4];
#pragma unroll
        for (int mt = 0; mt < 4; ++mt) {
            size_t row = (size_t)b * 1024 + s0 + mt * 16 + l16;
            af[mt] = *(const f16x8*)(out16 + row * 512 + kt * 32 + q * 8);
        }
        f16x8 bfg[8];
#pragma unroll
        for (int nt = 0; nt < 8; ++nt) {
            int ncol = w * 128 + nt * 16 + l16;
            bfg[nt] = *(const f16x8*)(W1t + (size_t)ncol * 512 + kt * 32 + q * 8);
        }
#pragma unroll
        for (int mt = 0; mt < 4; ++mt)
#pragma unroll
            for (int nt = 0; nt < 8; ++nt)
                acc[mt][nt] = MFMA16(af[mt], bfg[nt], acc[mt][nt]);
    }
    float b1v[8], w2v[8];
#pragma unroll
    for (int nt = 0; nt < 8; ++nt) {
        int ncol = w * 128 + nt * 16 + l16;
        b1v[nt] = b1[ncol];
        w2v[nt] = w2[ncol];
    }
    __shared__ float spart[4][64];
    float rs[4][4];
#pragma unroll
    for (int mt = 0; mt < 4; ++mt)
#pragma unroll
        for (int r = 0; r < 4; ++r) {
            float ssum = 0.f;
#pragma unroll
            for (int nt = 0; nt < 8; ++nt) {
                float xv = acc[mt][nt][r] + b1v[nt];
                float t = 1.f - 2.f / (1.f + __expf(2.f * xv));
                ssum += t * w2v[nt];
            }
            rs[mt][r] = ssum;
        }
#pragma unroll
    for (int off = 1; off < 16; off <<= 1)
#pragma unroll
        for (int mt = 0; mt < 4; ++mt)
#pragma unroll
            for (int r = 0; r < 4; ++r)
                rs[mt][r] += __shfl_xor(rs[mt][r], off, 64);
    if (l16 == 0) {
#pragma unroll
        for (int mt = 0; mt < 4; ++mt)
#pragma unroll
            for (int r = 0; r < 4; ++r)
                spart[w][mt * 16 + q * 4 + r] = rs[mt][r];
    }
    __syncthreads();
    if (tid < 64) {
        float v = spart[0][tid] + spart[1][tid] + spart[2][tid] + spart[3][tid] + b2[0];
        scores[b * 1024 + s0 + tid] = v;
    }
}

// K3b1: softmax over time per batch.
__global__ void k3_softmax(const float* __restrict__ scores, float* __restrict__ attn)
{
    int b = blockIdx.x, tid = threadIdx.x;
    __shared__ float red[4];
    f32x4 v = *(const f32x4*)(scores + b * 1024 + tid * 4);
    float m = fmaxf(fmaxf(v[0], v[1]), fmaxf(v[2], v[3]));
#pragma unroll
    for (int off = 1; off < 64; off <<= 1) m = fmaxf(m, __shfl_xor(m, off, 64));
    if ((tid & 63) == 0) red[tid >> 6] = m;
    __syncthreads();
    m = fmaxf(fmaxf(red[0], red[1]), fmaxf(red[2], red[3]));
    __syncthreads();
    float e0 = __expf(v[0] - m), e1 = __expf(v[1] - m), e2 = __expf(v[2] - m), e3 = __expf(v[3] - m);
    float ssum = e0 + e1 + e2 + e3;
#pragma unroll
    for (int off = 1; off < 64; off <<= 1) ssum += __shfl_xor(ssum, off, 64);
    if ((tid & 63) == 0) red[tid >> 6] = ssum;
    __syncthreads();
    float inv = 1.f / (red[0] + red[1] + red[2] + red[3]);
    f32x4 o = {e0 * inv, e1 * inv, e2 * inv, e3 * inv};
    *(f32x4*)(attn + b * 1024 + tid * 4) = o;
}

// K3b2: partial weighted sums over s-chunks of 128.
__global__ void k3_wsum(const f16* __restrict__ out16, const float* __restrict__ attn,
                        float* __restrict__ part)
{
    int bid = blockIdx.x;
    int b = bid >> 3, ch = bid & 7;
    int tid = threadIdx.x;
    const f16* op = out16 + ((size_t)b * 1024 + ch * 128) * 512 + tid * 2;
    const float* ap = attn + b * 1024 + ch * 128;
    float a0 = 0.f, a1 = 0.f;
#pragma unroll 4
    for (int i = 0; i < 128; ++i) {
        float aw = ap[i];
        f16x2 xv = *(const f16x2*)(op + (size_t)i * 512);
        a0 += aw * (float)xv[0];
        a1 += aw * (float)xv[1];
    }
    part[(size_t)(b * 8 + ch) * 512 + tid * 2] = a0;
    part[(size_t)(b * 8 + ch) * 512 + tid * 2 + 1] = a1;
}

// K3b3: reduce 8 partials -> context (fp32 output).
__global__ void k3_final(const float* __restrict__ part, float* __restrict__ outp)
{
    int b = blockIdx.x, tid = threadIdx.x;
#pragma unroll
    for (int j = 0; j < 2; ++j) {
        int cc = tid * 2 + j;
        float ssum = 0.f;
#pragma unroll
        for (int ch = 0; ch < 8; ++ch) ssum += part[(size_t)(b * 8 + ch) * 512 + cc];
        outp[b * 512 + cc] = ssum;
    }
}

extern "C" void kernel_launch(void* const* d_in, const int* in_sizes, int n_in,
                              void* d_out, int out_size, void* d_ws, size_t ws_size,
                              hipStream_t stream)
{
    const float* x   = (const float*)d_in[0];
    const float* Wzf = (const float*)d_in[1];
    const float* Uzf = (const float*)d_in[2];
    const float* bzf = (const float*)d_in[3];
    const float* Whf = (const float*)d_in[4];
    const float* Uhf = (const float*)d_in[5];
    const float* bhf = (const float*)d_in[6];
    const float* Wzb = (const float*)d_in[7];
    const float* Uzb = (const float*)d_in[8];
    const float* bzb = (const float*)d_in[9];
    const float* Whb = (const float*)d_in[10];
    const float* Uhb = (const float*)d_in[11];
    const float* bhb = (const float*)d_in[12];
    const float* W1  = (const float*)d_in[13];
    const float* b1  = (const float*)d_in[14];
    const float* w2  = (const float*)d_in[15];
    const float* b2  = (const float*)d_in[16];
    float* outp = (float*)d_out;

    char* ws = (char*)d_ws;
    f16* Ut    = (f16*)(ws + UT_OFF);
    f16* Wt    = (f16*)(ws + WT_OFF);
    f16* W1t   = (f16*)(ws + W1T_OFF);
    f16* xp2   = (f16*)(ws + XP_OFF);
    f16* o16   = (f16*)(ws + OUT_OFF);
    float* sc  = (float*)(ws + SC_OFF);
    float* at  = (float*)(ws + AT_OFF);
    float* pt  = (float*)(ws + PART_OFF);

    hipLaunchKernelGGL(k0_prep, dim3(256), dim3(256), 0, stream,
                       Uzf, Uhf, Uzb, Uhb, Wzf, Whf, Wzb, Whb, W1, Ut, Wt, W1t);
    hipLaunchKernelGGL(k1_xproj, dim3(8192), dim3(256), 0, stream,
                       x, Wt, bzf, bhf, bzb, bhb, xp2);
    hipLaunchKernelGGL(k2_gru, dim3(8), dim3(512), 0, stream, Ut, xp2, o16);
    hipLaunchKernelGGL(k3_scores, dim3(1024), dim3(256), 0, stream, o16, W1t, b1, w2, b2, sc);
    hipLaunchKernelGGL(k3_softmax, dim3(64), dim3(256), 0, stream, sc, at);
    hipLaunchKernelGGL(k3_wsum, dim3(512), dim3(256), 0, stream, o16, at, pt);
    hipLaunchKernelGGL(k3_final, dim3(64), dim3(256), 0, stream, pt, outp);
}